// Round 1
// baseline (646.576 us; speedup 1.0000x reference)
//
#include <hip/hip_runtime.h>

#define BETA   0.9f
#define T_STEPS 32
#define N_IN   256
#define N_H    64
#define N_C    3
#define BLOCK  256            // threads per block == samples per block
#define KT     32             // k-tile width
#define NKT    (N_IN / KT)    // 8 tiles

__global__ __launch_bounds__(BLOCK, 2) void snn_fused_kernel(
    const float* __restrict__ x,    // (B, 256)
    const float* __restrict__ W1,   // (64, 256)
    const float* __restrict__ W2,   // (3, 64)
    float* __restrict__ out)        // (B, 3)
{
    // transposed x tile: [k][sample], pad row to 257 words -> conflict-free
    __shared__ float xt[KT][BLOCK + 1];

    const int tid = threadIdx.x;
    const int b0  = blockIdx.x * BLOCK;
    const int b   = b0 + tid;

    float I1[N_H];
#pragma unroll
    for (int j = 0; j < N_H; ++j) I1[j] = 0.f;

    // ---------- Phase 1: I1 = x @ W1^T (fp32, ascending-k serial order) ----------
#pragma unroll 1
    for (int kt = 0; kt < NKT; ++kt) {
        __syncthreads();   // previous tile's reads done before overwrite
        // stage x[b0:b0+256][kt*32 : kt*32+32] transposed into LDS
#pragma unroll
        for (int i = 0; i < 8; ++i) {
            int L  = tid + i * BLOCK;   // float4 index 0..2047
            int s  = L >> 3;            // sample row 0..255
            int k4 = L & 7;             // float4 within row
            const float4 v = *reinterpret_cast<const float4*>(
                x + (size_t)(b0 + s) * N_IN + kt * KT + k4 * 4);
            xt[k4 * 4 + 0][s] = v.x;
            xt[k4 * 4 + 1][s] = v.y;
            xt[k4 * 4 + 2][s] = v.z;
            xt[k4 * 4 + 3][s] = v.w;
        }
        __syncthreads();

        // my sample's 32 x-values for this k-tile
        float xv[KT];
#pragma unroll
        for (int kk = 0; kk < KT; ++kk) xv[kk] = xt[kk][tid];

        // 64 x 32 FMAs; W1 has wave-uniform address -> s_load, SGPR operand
#pragma unroll
        for (int j = 0; j < N_H; ++j) {
            const float* w = W1 + j * N_IN + kt * KT;
            float acc = I1[j];
#pragma unroll
            for (int kk = 0; kk < KT; ++kk)
                acc = fmaf(xv[kk], w[kk], acc);
            I1[j] = acc;
        }
    }

    // ---------- Phase 2: LIF dynamics, t-outer / j-unrolled ----------
    float v1[N_H];
#pragma unroll
    for (int j = 0; j < N_H; ++j) v1[j] = 0.f;
    float v2a = 0.f, v2b = 0.f, v2c = 0.f;
    float c0 = 0.f, c1 = 0.f, c2 = 0.f;

#pragma unroll 1
    for (int t = 0; t < T_STEPS; ++t) {
        float d0 = 0.f, d1 = 0.f, d2 = 0.f;
#pragma unroll
        for (int j = 0; j < N_H; ++j) {
            float v = fmaf(BETA, v1[j], I1[j]);      // leak + input
            float s = (v >= 1.0f) ? 1.0f : 0.0f;     // Heaviside(v - THR)
            v1[j] = v - s;                           // reset by subtraction
            // drive accumulation, ascending-j serial order (s*w exact: s in {0,1})
            d0 = fmaf(s, W2[0 * N_H + j], d0);
            d1 = fmaf(s, W2[1 * N_H + j], d1);
            d2 = fmaf(s, W2[2 * N_H + j], d2);
        }
        // layer-2 LIF + spike count
        {
            float v = fmaf(BETA, v2a, d0);
            float s = (v >= 1.0f) ? 1.0f : 0.0f;
            v2a = v - s;  c0 += s;
        }
        {
            float v = fmaf(BETA, v2b, d1);
            float s = (v >= 1.0f) ? 1.0f : 0.0f;
            v2b = v - s;  c1 += s;
        }
        {
            float v = fmaf(BETA, v2c, d2);
            float s = (v >= 1.0f) ? 1.0f : 0.0f;
            v2c = v - s;  c2 += s;
        }
    }

    out[(size_t)b * N_C + 0] = c0;
    out[(size_t)b * N_C + 1] = c1;
    out[(size_t)b * N_C + 2] = c2;
}

extern "C" void kernel_launch(void* const* d_in, const int* in_sizes, int n_in,
                              void* d_out, int out_size, void* d_ws, size_t ws_size,
                              hipStream_t stream) {
    const float* x  = (const float*)d_in[0];
    const float* W1 = (const float*)d_in[1];
    const float* W2 = (const float*)d_in[2];
    float* out = (float*)d_out;

    const int B = in_sizes[0] / N_IN;          // 131072
    snn_fused_kernel<<<B / BLOCK, BLOCK, 0, stream>>>(x, W1, W2, out);
}

// Round 2
// 561.692 us; speedup vs baseline: 1.1511x; 1.1511x over previous
//
#include <hip/hip_runtime.h>

#define BETA    0.9f
#define T_STEPS 32
#define N_IN    256
#define N_H     64
#define N_C     3
#define BLOCK   128            // 2 waves per block
#define SAMPLES 64             // samples per block (lane = sample)
#define HALF    32             // hidden neurons per wave
#define KT      32             // k-tile width
#define NKT     (N_IN / KT)    // 8 tiles

// wave0 owns j = 0..31, wave1 owns j = 32..63 of the SAME 64 samples.
// Drive sum d_c = sum_j s_j * W2[c][j] is kept in strict ascending-j serial
// fma order: wave0 computes the j<32 prefix, hands it to wave1 via LDS,
// wave1 continues j>=32 and runs layer 2. t-loop is pipelined one step deep.
__global__ __launch_bounds__(BLOCK, 1) void snn_fused_kernel(
    const float* __restrict__ x,    // (B, 256)
    const float* __restrict__ W1,   // (64, 256)
    const float* __restrict__ W2,   // (3, 64)
    float* __restrict__ out)        // (B, 3)
{
    __shared__ float xt[KT][SAMPLES + 1];   // transposed x tile, 2-way banks only
    __shared__ float dbuf[2][SAMPLES][3];   // wave0 -> wave1 partial drives

    const int tid  = threadIdx.x;
    const int lane = tid & 63;              // sample within block
    const int wv   = tid >> 6;              // 0 or 1
    const int b0   = blockIdx.x * SAMPLES;
    const int b    = b0 + lane;
    const int jb   = wv * HALF;             // my j-range base

    float I1[HALF];
#pragma unroll
    for (int j = 0; j < HALF; ++j) I1[j] = 0.f;

    // ---------- Phase 1: I1[jb..jb+31] = x_row @ W1[jb..jb+31]^T ----------
#pragma unroll 1
    for (int kt = 0; kt < NKT; ++kt) {
        __syncthreads();
        // stage x[b0..b0+64][kt*32..+32] transposed; 512 float4, 128 threads
#pragma unroll
        for (int i = 0; i < 4; ++i) {
            int L  = tid + i * BLOCK;       // float4 id 0..511
            int s  = L >> 3;                // sample 0..63
            int k4 = L & 7;                 // float4 within row
            const float4 v = *reinterpret_cast<const float4*>(
                x + (size_t)(b0 + s) * N_IN + kt * KT + k4 * 4);
            xt[k4 * 4 + 0][s] = v.x;
            xt[k4 * 4 + 1][s] = v.y;
            xt[k4 * 4 + 2][s] = v.z;
            xt[k4 * 4 + 3][s] = v.w;
        }
        __syncthreads();

        float xv[KT];
#pragma unroll
        for (int kk = 0; kk < KT; ++kk) xv[kk] = xt[kk][lane];

#pragma unroll
        for (int jj = 0; jj < HALF; ++jj) {
            const float* w = W1 + (size_t)(jb + jj) * N_IN + kt * KT;  // wave-uniform
            float acc = I1[jj];
#pragma unroll
            for (int kk = 0; kk < KT; ++kk)
                acc = fmaf(xv[kk], w[kk], acc);
            I1[jj] = acc;
        }
    }
    __syncthreads();

    // ---------- Phase 2: pipelined LIF ----------
    const float* w2r0 = W2 + 0 * N_H + jb;   // wave-uniform rows
    const float* w2r1 = W2 + 1 * N_H + jb;
    const float* w2r2 = W2 + 2 * N_H + jb;

    float v1[HALF];
#pragma unroll
    for (int j = 0; j < HALF; ++j) v1[j] = 0.f;
    float v2a = 0.f, v2b = 0.f, v2c = 0.f;
    float c0 = 0.f, c1 = 0.f, c2 = 0.f;

#pragma unroll 1
    for (int it = 0; it < T_STEPS + 1; ++it) {
        if (wv == 0) {
            if (it < T_STEPS) {
                float d0 = 0.f, d1 = 0.f, d2 = 0.f;
#pragma unroll
                for (int jj = 0; jj < HALF; ++jj) {
                    float v = fmaf(BETA, v1[jj], I1[jj]);
                    float s = (v >= 1.0f) ? 1.0f : 0.0f;
                    v1[jj] = v - s;
                    d0 = fmaf(s, w2r0[jj], d0);
                    d1 = fmaf(s, w2r1[jj], d1);
                    d2 = fmaf(s, w2r2[jj], d2);
                }
                dbuf[it & 1][lane][0] = d0;
                dbuf[it & 1][lane][1] = d1;
                dbuf[it & 1][lane][2] = d2;
            }
        } else {
            if (it >= 1) {
                float d0 = dbuf[(it - 1) & 1][lane][0];
                float d1 = dbuf[(it - 1) & 1][lane][1];
                float d2 = dbuf[(it - 1) & 1][lane][2];
#pragma unroll
                for (int jj = 0; jj < HALF; ++jj) {
                    float v = fmaf(BETA, v1[jj], I1[jj]);
                    float s = (v >= 1.0f) ? 1.0f : 0.0f;
                    v1[jj] = v - s;
                    d0 = fmaf(s, w2r0[jj], d0);   // continues serial j-order
                    d1 = fmaf(s, w2r1[jj], d1);
                    d2 = fmaf(s, w2r2[jj], d2);
                }
                {
                    float v = fmaf(BETA, v2a, d0);
                    float s = (v >= 1.0f) ? 1.0f : 0.0f;
                    v2a = v - s;  c0 += s;
                }
                {
                    float v = fmaf(BETA, v2b, d1);
                    float s = (v >= 1.0f) ? 1.0f : 0.0f;
                    v2b = v - s;  c1 += s;
                }
                {
                    float v = fmaf(BETA, v2c, d2);
                    float s = (v >= 1.0f) ? 1.0f : 0.0f;
                    v2c = v - s;  c2 += s;
                }
            }
        }
        __syncthreads();
    }

    if (wv == 1) {
        out[(size_t)b * N_C + 0] = c0;
        out[(size_t)b * N_C + 1] = c1;
        out[(size_t)b * N_C + 2] = c2;
    }
}

extern "C" void kernel_launch(void* const* d_in, const int* in_sizes, int n_in,
                              void* d_out, int out_size, void* d_ws, size_t ws_size,
                              hipStream_t stream) {
    const float* x  = (const float*)d_in[0];
    const float* W1 = (const float*)d_in[1];
    const float* W2 = (const float*)d_in[2];
    float* out = (float*)d_out;

    const int B = in_sizes[0] / N_IN;              // 131072
    snn_fused_kernel<<<B / SAMPLES, BLOCK, 0, stream>>>(x, W1, W2, out);
}

// Round 3
// 283.236 us; speedup vs baseline: 2.2828x; 1.9831x over previous
//
#include <hip/hip_runtime.h>

#define BETA    0.9f
#define T_STEPS 32
#define N_IN    256
#define N_H     64
#define N_C     3
#define BLOCK   128            // 2 waves per block
#define SAMPLES 64             // samples per block (lane = sample)
#define HALF    32             // hidden neurons per wave
#define KT      32             // k-tile width
#define NKT     (N_IN / KT)    // 8 tiles
#define XP      68             // padded LDS row (272 B, 16B-aligned, bank-skewed)

// wave0 owns j=0..31, wave1 owns j=32..63 of the same 64 samples.
// All weight reads are wave-uniform LDS broadcasts (never VMEM in hot loops).
// Reduction orders preserved exactly: I1 ascending-k serial fma per j;
// drives ascending-j serial fma (wave0 prefix -> LDS -> wave1 suffix).
__global__ __launch_bounds__(BLOCK, 4) void snn_fused_kernel(
    const float* __restrict__ x,    // (B, 256)
    const float* __restrict__ W1,   // (64, 256)
    const float* __restrict__ W2,   // (3, 64)
    float* __restrict__ out)        // (B, 3)
{
    __shared__ float xt [KT][XP];          // x tile, transposed: [k][sample]
    __shared__ float w1t[KT][XP];          // W1 tile, transposed: [k][j]
    __shared__ float w2l[N_C][N_H];        // W2 rows
    __shared__ float dbuf[2][SAMPLES][4];  // wave0 -> wave1 partial drives

    const int tid  = threadIdx.x;
    const int lane = tid & 63;             // sample within block
    const int wv   = tid >> 6;             // 0 or 1
    const int b0   = blockIdx.x * SAMPLES;
    const int b    = b0 + lane;
    const int jb   = wv * HALF;            // my j-range base

    // stage W2 once (192 floats)
    for (int i = tid; i < N_C * N_H; i += BLOCK)
        (&w2l[0][0])[i] = W2[i];

    float I1[HALF];
#pragma unroll
    for (int j = 0; j < HALF; ++j) I1[j] = 0.f;

    // ---------- Phase 1: I1[jb..jb+31] = x_row @ W1[jb..jb+31]^T ----------
#pragma unroll 1
    for (int kt = 0; kt < NKT; ++kt) {
        __syncthreads();   // previous tile fully consumed (also fences w2l stage)
        // stage x[b0..b0+64][kt*32..+32] transposed: 512 float4 by 128 threads
#pragma unroll
        for (int i = 0; i < 4; ++i) {
            int L  = tid + i * BLOCK;      // float4 id 0..511
            int s  = L >> 3;               // sample 0..63
            int k4 = L & 7;                // float4 within row
            const float4 v = *reinterpret_cast<const float4*>(
                x + (size_t)(b0 + s) * N_IN + kt * KT + k4 * 4);
            xt[k4 * 4 + 0][s] = v.x;
            xt[k4 * 4 + 1][s] = v.y;
            xt[k4 * 4 + 2][s] = v.z;
            xt[k4 * 4 + 3][s] = v.w;
        }
        // stage W1 tile transposed: w1t[k][j] = W1[j][kt*32+k]
#pragma unroll
        for (int i = 0; i < 4; ++i) {
            int L  = tid + i * BLOCK;      // float4 id 0..511
            int j  = L >> 3;               // 0..63
            int k4 = L & 7;                // 0..7
            const float4 v = *reinterpret_cast<const float4*>(
                W1 + (size_t)j * N_IN + kt * KT + k4 * 4);
            w1t[k4 * 4 + 0][j] = v.x;
            w1t[k4 * 4 + 1][j] = v.y;
            w1t[k4 * 4 + 2][j] = v.z;
            w1t[k4 * 4 + 3][j] = v.w;
        }
        __syncthreads();

        // kk-outer / j-inner: 32 independent FMA chains, uniform b128 W reads.
        // Per-I1[j] order is still ascending k (serial), unchanged arithmetic.
#pragma unroll
        for (int kk = 0; kk < KT; ++kk) {
            const float xk = xt[kk][lane];            // per-lane, 2-way banks (free)
#pragma unroll
            for (int g = 0; g < HALF / 4; ++g) {
                const float4 w = *reinterpret_cast<const float4*>(
                    &w1t[kk][jb + g * 4]);            // wave-uniform -> broadcast
                I1[g * 4 + 0] = fmaf(xk, w.x, I1[g * 4 + 0]);
                I1[g * 4 + 1] = fmaf(xk, w.y, I1[g * 4 + 1]);
                I1[g * 4 + 2] = fmaf(xk, w.z, I1[g * 4 + 2]);
                I1[g * 4 + 3] = fmaf(xk, w.w, I1[g * 4 + 3]);
            }
        }
    }
    __syncthreads();

    // ---------- Phase 2: pipelined LIF, W2 via uniform LDS broadcast ----------
    float v1[HALF];
#pragma unroll
    for (int j = 0; j < HALF; ++j) v1[j] = 0.f;
    float v2a = 0.f, v2b = 0.f, v2c = 0.f;
    float c0 = 0.f, c1 = 0.f, c2 = 0.f;

#pragma unroll 1
    for (int it = 0; it < T_STEPS + 1; ++it) {
        if (wv == 0) {
            if (it < T_STEPS) {
                float d0 = 0.f, d1 = 0.f, d2 = 0.f;
#pragma unroll
                for (int g = 0; g < HALF / 4; ++g) {
                    const float4 wa = *reinterpret_cast<const float4*>(&w2l[0][jb + g * 4]);
                    const float4 wb = *reinterpret_cast<const float4*>(&w2l[1][jb + g * 4]);
                    const float4 wc = *reinterpret_cast<const float4*>(&w2l[2][jb + g * 4]);
#pragma unroll
                    for (int e = 0; e < 4; ++e) {
                        const int jj = g * 4 + e;
                        float v = fmaf(BETA, v1[jj], I1[jj]);
                        float s = (v >= 1.0f) ? 1.0f : 0.0f;
                        v1[jj] = v - s;
                        d0 = fmaf(s, (&wa.x)[e], d0);
                        d1 = fmaf(s, (&wb.x)[e], d1);
                        d2 = fmaf(s, (&wc.x)[e], d2);
                    }
                }
                dbuf[it & 1][lane][0] = d0;
                dbuf[it & 1][lane][1] = d1;
                dbuf[it & 1][lane][2] = d2;
            }
        } else {
            if (it >= 1) {
                float d0 = dbuf[(it - 1) & 1][lane][0];
                float d1 = dbuf[(it - 1) & 1][lane][1];
                float d2 = dbuf[(it - 1) & 1][lane][2];
#pragma unroll
                for (int g = 0; g < HALF / 4; ++g) {
                    const float4 wa = *reinterpret_cast<const float4*>(&w2l[0][jb + g * 4]);
                    const float4 wb = *reinterpret_cast<const float4*>(&w2l[1][jb + g * 4]);
                    const float4 wc = *reinterpret_cast<const float4*>(&w2l[2][jb + g * 4]);
#pragma unroll
                    for (int e = 0; e < 4; ++e) {
                        const int jj = g * 4 + e;
                        float v = fmaf(BETA, v1[jj], I1[jj]);
                        float s = (v >= 1.0f) ? 1.0f : 0.0f;
                        v1[jj] = v - s;
                        d0 = fmaf(s, (&wa.x)[e], d0);   // continues serial j-order
                        d1 = fmaf(s, (&wb.x)[e], d1);
                        d2 = fmaf(s, (&wc.x)[e], d2);
                    }
                }
                {
                    float v = fmaf(BETA, v2a, d0);
                    float s = (v >= 1.0f) ? 1.0f : 0.0f;
                    v2a = v - s;  c0 += s;
                }
                {
                    float v = fmaf(BETA, v2b, d1);
                    float s = (v >= 1.0f) ? 1.0f : 0.0f;
                    v2b = v - s;  c1 += s;
                }
                {
                    float v = fmaf(BETA, v2c, d2);
                    float s = (v >= 1.0f) ? 1.0f : 0.0f;
                    v2c = v - s;  c2 += s;
                }
            }
        }
        __syncthreads();
    }

    if (wv == 1) {
        out[(size_t)b * N_C + 0] = c0;
        out[(size_t)b * N_C + 1] = c1;
        out[(size_t)b * N_C + 2] = c2;
    }
}

extern "C" void kernel_launch(void* const* d_in, const int* in_sizes, int n_in,
                              void* d_out, int out_size, void* d_ws, size_t ws_size,
                              hipStream_t stream) {
    const float* x  = (const float*)d_in[0];
    const float* W1 = (const float*)d_in[1];
    const float* W2 = (const float*)d_in[2];
    float* out = (float*)d_out;

    const int B = in_sizes[0] / N_IN;              // 131072
    snn_fused_kernel<<<B / SAMPLES, BLOCK, 0, stream>>>(x, W1, W2, out);
}